// Round 4
// baseline (385.217 us; speedup 1.0000x reference)
//
#include <hip/hip_runtime.h>
#include <hip/hip_bf16.h>

typedef __attribute__((ext_vector_type(8))) short short8;
typedef __attribute__((ext_vector_type(4))) float f32x4;

#define N0 65536
#define N1 16384
#define N2 4096
#define N3 1024

// ---------------------------------------------------------------------------
// Weight prep (all 4 tensors in one launch; dst buffers contiguous):
// Wt[k][d][c] = bf16(W[k][c][d])
// ---------------------------------------------------------------------------
__global__ void prep_w4(const float* __restrict__ A, const float* __restrict__ B,
                        const float* __restrict__ C, const float* __restrict__ D,
                        __hip_bfloat16* __restrict__ dst, int total)
{
    int i = blockIdx.x * 256 + threadIdx.x;
    if (i >= total) return;
    int k = i >> 12, r = i & 4095, d = r >> 6, c = r & 63;
    const float* src; int kl;
    if (k < 27)      { src = A; kl = k; }
    else if (k < 54) { src = B; kl = k - 27; }
    else if (k < 81) { src = C; kl = k - 54; }
    else             { src = D; kl = k - 81; }
    dst[i] = __float2bfloat16(src[(kl << 12) + (c << 6) + d]);
}

// ---------------------------------------------------------------------------
// MFMA sparse conv: out[n,d] = sum_k sum_c feat[nmap[n,k],c] * W[k][c][d]
// feat bf16 [Nin][64]; Wt bf16 [K][d][c]; 64 output rows/block, 4 waves.
// mode 0: store bf16 raw; mode 2: bf16 bias+relu.
// 2-buffer LDS pipeline with COUNTED vmcnt(4): tile k's loads (issued one
// full iteration ago) are waited on while tile k+1's 4 loads stay in flight
// across the barrier (T3/T4 minimum recipe, never vmcnt(0) mid-loop).
// LDS XOR-swizzle: 16B-block q of row r holds global block q^(r&7) (rule #21).
// ---------------------------------------------------------------------------
__global__ __launch_bounds__(256) void spconv_mfma(
    const __hip_bfloat16* __restrict__ feat, const int* __restrict__ nmap,
    const __hip_bfloat16* __restrict__ Wt, void* __restrict__ outp,
    const float* __restrict__ bias, int Nout, int K, int mode)
{
    __shared__ short Abuf[2][64 * 64];
    __shared__ short Bbuf[2][64 * 64];
    __shared__ int jl[27 * 64];

    const int t = threadIdx.x;
    const int w = t >> 6, l = t & 63;
    const int row0 = blockIdx.x * 64;

    for (int i = t; i < K * 64; i += 256) {
        int k = i >> 6, r = i & 63;
        jl[i] = nmap[(size_t)(row0 + r) * K + k];
    }
    __syncthreads();

    // staging geometry: slot = w*128 + i*64 + l ; r = slot>>3, q = slot&7
    const int rr0 = (w << 4) + (l >> 3);        // i=0 row, +8 for i=1
    const int qq = (l & 7) ^ (l >> 3);          // inverse-swizzled 16B block

    auto stage = [&](int buf, int k) {
        const __hip_bfloat16* Wk = Wt + (size_t)k * 4096;
#pragma unroll
        for (int i = 0; i < 2; ++i) {
            int rr = rr0 + (i << 3);
            int j = jl[(k << 6) + rr];
            const __hip_bfloat16* asrc = feat + ((size_t)j << 6) + (qq << 3);
            __builtin_amdgcn_global_load_lds(
                (const __attribute__((address_space(1))) void*)asrc,
                (__attribute__((address_space(3))) void*)&Abuf[buf][(w << 10) + (i << 9)],
                16, 0, 0);
            const __hip_bfloat16* bsrc = Wk + (rr << 6) + (qq << 3);
            __builtin_amdgcn_global_load_lds(
                (const __attribute__((address_space(1))) void*)bsrc,
                (__attribute__((address_space(3))) void*)&Bbuf[buf][(w << 10) + (i << 9)],
                16, 0, 0);
        }
    };

    f32x4 acc[4] = {};
    const int lr = l & 15, lh = l >> 4;
    const int arow = (w << 4) + lr;

    stage(0, 0);

    int cur = 0;
    for (int k = 0; k < K; ++k) {
        if (k + 1 < K) {
            stage(cur ^ 1, k + 1);
            asm volatile("s_waitcnt vmcnt(4)" ::: "memory");  // tile k done; k+1 in flight
        } else {
            asm volatile("s_waitcnt vmcnt(0)" ::: "memory");
        }
        __syncthreads();   // all waves' tile-k loads landed; prior reads of buf cur^1 done
        const short* Ab = Abuf[cur];
        const short* Bb = Bbuf[cur];
#pragma unroll
        for (int kk = 0; kk < 2; ++kk) {
            int q = (kk << 2) + lh;
            short8 a = *(const short8*)&Ab[(arow << 6) + ((q ^ (arow & 7)) << 3)];
#pragma unroll
            for (int ct = 0; ct < 4; ++ct) {
                int drow = (ct << 4) + lr;
                short8 b = *(const short8*)&Bb[(drow << 6) + ((q ^ (drow & 7)) << 3)];
                acc[ct] = __builtin_amdgcn_mfma_f32_16x16x32_bf16(a, b, acc[ct], 0, 0, 0);
            }
        }
        __syncthreads();   // compute(k) reads done before next iter overwrites buf cur
        cur ^= 1;
    }

    // epilogue: C/D layout col = lane&15 (+ct*16), row = (lane>>4)*4 + reg
    __hip_bfloat16* ob = (__hip_bfloat16*)outp;
#pragma unroll
    for (int ct = 0; ct < 4; ++ct) {
        int col = (ct << 4) + lr;
        float bv = (mode == 2) ? bias[col] : 0.f;
#pragma unroll
        for (int r = 0; r < 4; ++r) {
            int row = row0 + (w << 4) + (lh << 2) + r;
            float v = acc[ct][r];
            if (mode == 2) v = fmaxf(v + bv, 0.f);
            ob[((size_t)row << 6) + col] = __float2bfloat16(v);
        }
    }
}

// ---------------------------------------------------------------------------
// epi_full: thread-per-row, LDS-staged weights (broadcast reads), fully
// unrolled register arrays (no runtime indexing -> no scratch).
//   t = act(src); hx = t@Wout + bout -> hx_out; g = sigmoid(hx@Wg + bg);
//   gout = bf16(g*t)
// smode 0: src bf16 +bias+relu; 2: src f32 raw.
// N is a multiple of 256 (1024..65536).
// ---------------------------------------------------------------------------
__global__ __launch_bounds__(256) void epi_full(
    const void* __restrict__ srcp, int smode, const float* __restrict__ bconv,
    const float* __restrict__ Wout, const float* __restrict__ bout,
    const float* __restrict__ Wg, const float* __restrict__ bg,
    float* __restrict__ hx_out, __hip_bfloat16* __restrict__ gout, int N)
{
    __shared__ float Woutl[64 * 32];
    __shared__ float Wgl[32 * 64];
    __shared__ float boutl[32];
    __shared__ float bgl[64];
    __shared__ float bcl[64];

    const int t = threadIdx.x;
    for (int i = t; i < 2048; i += 256) { Woutl[i] = Wout[i]; Wgl[i] = Wg[i]; }
    if (t < 32) boutl[t] = bout[t];
    if (t >= 64 && t < 128) bgl[t - 64] = bg[t - 64];
    if (t >= 128 && t < 192) bcl[t - 128] = bconv ? bconv[t - 128] : 0.f;
    __syncthreads();

    const int row = blockIdx.x * 256 + t;

    float tv[64];
    if (smode == 0) {
        const ushort4* sb = (const ushort4*)((const __hip_bfloat16*)srcp + ((size_t)row << 6));
#pragma unroll
        for (int i = 0; i < 16; ++i) {
            ushort4 v = sb[i];
            tv[i * 4 + 0] = __bfloat162float(__builtin_bit_cast(__hip_bfloat16, v.x));
            tv[i * 4 + 1] = __bfloat162float(__builtin_bit_cast(__hip_bfloat16, v.y));
            tv[i * 4 + 2] = __bfloat162float(__builtin_bit_cast(__hip_bfloat16, v.z));
            tv[i * 4 + 3] = __bfloat162float(__builtin_bit_cast(__hip_bfloat16, v.w));
        }
    } else {
        const float4* sf = (const float4*)((const float*)srcp + ((size_t)row << 6));
#pragma unroll
        for (int i = 0; i < 16; ++i) {
            float4 v = sf[i];
            tv[i * 4 + 0] = v.x; tv[i * 4 + 1] = v.y;
            tv[i * 4 + 2] = v.z; tv[i * 4 + 3] = v.w;
        }
    }
    if (smode != 2) {
#pragma unroll
        for (int c = 0; c < 64; ++c) tv[c] = fmaxf(tv[c] + bcl[c], 0.f);
    }

    // ---- hx = t @ Wout + bout ----
    float hx[32];
#pragma unroll
    for (int d = 0; d < 32; ++d) hx[d] = boutl[d];
#pragma unroll
    for (int c = 0; c < 64; ++c) {
        float tc = tv[c];
        const f32x4* wr = (const f32x4*)&Woutl[c << 5];
#pragma unroll
        for (int d4 = 0; d4 < 8; ++d4) {
            f32x4 wv = wr[d4];
            hx[d4 * 4 + 0] = fmaf(tc, wv[0], hx[d4 * 4 + 0]);
            hx[d4 * 4 + 1] = fmaf(tc, wv[1], hx[d4 * 4 + 1]);
            hx[d4 * 4 + 2] = fmaf(tc, wv[2], hx[d4 * 4 + 2]);
            hx[d4 * 4 + 3] = fmaf(tc, wv[3], hx[d4 * 4 + 3]);
        }
    }
    {
        float* ho = hx_out + ((size_t)row << 5);
#pragma unroll
        for (int i = 0; i < 8; ++i) {
            float4 v = {hx[i * 4 + 0], hx[i * 4 + 1], hx[i * 4 + 2], hx[i * 4 + 3]};
            ((float4*)ho)[i] = v;
        }
    }

    // ---- g = sigmoid(hx @ Wg + bg); gout = bf16(g * t) ----
    __hip_bfloat16* go = gout + ((size_t)row << 6);
#pragma unroll
    for (int jc = 0; jc < 2; ++jc) {
        float acc[32];
#pragma unroll
        for (int jj = 0; jj < 32; ++jj) acc[jj] = bgl[jc * 32 + jj];
#pragma unroll
        for (int d = 0; d < 32; ++d) {
            float hd = hx[d];
            const f32x4* wr = (const f32x4*)&Wgl[(d << 6) + jc * 32];
#pragma unroll
            for (int j4 = 0; j4 < 8; ++j4) {
                f32x4 wv = wr[j4];
                acc[j4 * 4 + 0] = fmaf(hd, wv[0], acc[j4 * 4 + 0]);
                acc[j4 * 4 + 1] = fmaf(hd, wv[1], acc[j4 * 4 + 1]);
                acc[j4 * 4 + 2] = fmaf(hd, wv[2], acc[j4 * 4 + 2]);
                acc[j4 * 4 + 3] = fmaf(hd, wv[3], acc[j4 * 4 + 3]);
            }
        }
        unsigned short ob[32];
#pragma unroll
        for (int jj = 0; jj < 32; ++jj) {
            float gg = 1.f / (1.f + __expf(-acc[jj]));
            ob[jj] = __builtin_bit_cast(unsigned short,
                         __float2bfloat16(gg * tv[jc * 32 + jj]));
        }
#pragma unroll
        for (int i = 0; i < 8; ++i) {
            ushort4 v = {ob[i * 4 + 0], ob[i * 4 + 1], ob[i * 4 + 2], ob[i * 4 + 3]};
            ((ushort4*)go)[jc * 8 + i] = v;
        }
    }
}

// ---------------------------------------------------------------------------
extern "C" void kernel_launch(void* const* d_in, const int* in_sizes, int n_in,
                              void* d_out, int out_size, void* d_ws, size_t ws_size,
                              hipStream_t stream)
{
    const float* x    = (const float*)d_in[0];
    const float* Wg0  = (const float*)d_in[1];
    const float* bg0  = (const float*)d_in[2];
    const float* Wg1  = (const float*)d_in[3];
    const float* bg1  = (const float*)d_in[4];
    const float* Wout = (const float*)d_in[5];
    const float* bout = (const float*)d_in[6];
    const float* WA   = (const float*)d_in[7];
    const float* bA   = (const float*)d_in[8];
    const float* WB   = (const float*)d_in[9];
    const float* bB   = (const float*)d_in[10];
    const float* WD   = (const float*)d_in[11];
    const float* bD   = (const float*)d_in[12];
    const float* WC   = (const float*)d_in[13];
    const float* bC   = (const float*)d_in[14];
    const int* nmap[4] = {(const int*)d_in[15], (const int*)d_in[16],
                          (const int*)d_in[17], (const int*)d_in[18]};
    const int* ndm[3]  = {(const int*)d_in[19], (const int*)d_in[20],
                          (const int*)d_in[21]};

    float* out = (float*)d_out;
    __hip_bfloat16* featbf0 = (__hip_bfloat16*)d_ws;
    __hip_bfloat16* featbf1 = featbf0 + (size_t)N0 * 64;
    __hip_bfloat16* convbf  = featbf1 + (size_t)N0 * 64;
    __hip_bfloat16* WAt = convbf + (size_t)N0 * 64;
    __hip_bfloat16* WBt = WAt + 27 * 4096;
    __hip_bfloat16* WCt = WBt + 27 * 4096;
    __hip_bfloat16* WDt = WCt + 27 * 4096;

    const int Ns[4] = {N0, N1, N2, N3};
    size_t off[7];
    off[0] = 0;
    off[1] = off[0] + (size_t)N0 * 32;
    off[2] = off[1] + (size_t)N0 * 32;
    off[3] = off[2] + (size_t)N1 * 32;
    off[4] = off[3] + (size_t)N1 * 32;
    off[5] = off[4] + (size_t)N2 * 32;
    off[6] = off[5] + (size_t)N2 * 32;

    hipLaunchKernelGGL(prep_w4, dim3((89 * 4096 + 255) / 256), dim3(256), 0, stream,
                       WA, WB, WC, WD, WAt, 89 * 4096);

    auto conv = [&](const __hip_bfloat16* fin, const int* nm,
                    const __hip_bfloat16* Wt, int Nout, int K,
                    const float* bias2, void* dst, int mode) {
        hipLaunchKernelGGL(spconv_mfma, dim3(Nout / 64), dim3(256), 0, stream,
                           fin, nm, Wt, dst, bias2, Nout, K, mode);
    };

    // init: hx0 -> out0 ; featbf0 = bf16(sigmoid(hx0@Wg0+bg0) * x)
    hipLaunchKernelGGL(epi_full, dim3(N0 / 256), dim3(256), 0, stream,
                       (const void*)x, 2, (const float*)nullptr, Wout, bout, Wg0, bg0,
                       out + off[0], featbf0, N0);

    for (int s = 0; s < 3; ++s) {
        int N = Ns[s], Nn = Ns[s + 1];

        // conv A (bias+relu fused, bf16 out) -> featbf1
        conv(featbf0, nmap[s], WAt, N, 27, bA, featbf1, 2);
        // conv B (raw bf16 out) -> convbf ; epilogue fuses bias+relu+hx+gate
        conv(featbf1, nmap[s], WBt, N, 27, nullptr, convbf, 0);
        hipLaunchKernelGGL(epi_full, dim3(N / 256), dim3(256), 0, stream,
                           (const void*)convbf, 0, bB, Wout, bout, Wg1, bg1,
                           out + off[s * 2 + 1], featbf0, N);

        // conv D (downsample, bias+relu fused) -> featbf1
        conv(featbf0, ndm[s], WDt, Nn, 8, bD, featbf1, 2);
        // conv C (raw bf16 out) -> convbf ; epilogue
        conv(featbf1, nmap[s + 1], WCt, Nn, 27, nullptr, convbf, 0);
        hipLaunchKernelGGL(epi_full, dim3(Nn / 256), dim3(256), 0, stream,
                           (const void*)convbf, 0, bC, Wout, bout, Wg0, bg0,
                           out + off[s * 2 + 2], featbf0, Nn);
    }
}

// Round 5
// 372.938 us; speedup vs baseline: 1.0329x; 1.0329x over previous
//
#include <hip/hip_runtime.h>
#include <hip/hip_bf16.h>

typedef __attribute__((ext_vector_type(8))) short short8;
typedef __attribute__((ext_vector_type(4))) float f32x4;

#define N0 65536
#define N1 16384
#define N2 4096
#define N3 1024

// ---------------------------------------------------------------------------
// Weight prep (all 4 tensors in one launch; dst buffers contiguous):
// Wt[k][d][c] = bf16(W[k][c][d])
// ---------------------------------------------------------------------------
__global__ void prep_w4(const float* __restrict__ A, const float* __restrict__ B,
                        const float* __restrict__ C, const float* __restrict__ D,
                        __hip_bfloat16* __restrict__ dst, int total)
{
    int i = blockIdx.x * 256 + threadIdx.x;
    if (i >= total) return;
    int k = i >> 12, r = i & 4095, d = r >> 6, c = r & 63;
    const float* src; int kl;
    if (k < 27)      { src = A; kl = k; }
    else if (k < 54) { src = B; kl = k - 27; }
    else if (k < 81) { src = C; kl = k - 54; }
    else             { src = D; kl = k - 81; }
    dst[i] = __float2bfloat16(src[(kl << 12) + (c << 6) + d]);
}

// ---------------------------------------------------------------------------
// MFMA sparse conv: out[n,d] = sum_k sum_c feat[nmap[n,k],c] * W[k][c][d]
// 128 threads = 2 waves; 64 output rows/block; each wave 32 rows x 64 cols
// (2 row-tiles x 4 col-tiles of 16x16x32 MFMA). Per tap per wave:
// 4 A + 8 B ds_read_b128 + 16 MFMA.
// Pipeline: double-buffered LDS, RAW s_barrier (no implicit vmcnt drain) +
// counted vmcnt(8): tile k+1's 8 global_load_lds stay in flight across both
// barriers, waited at iter k+1 (T3/T4). Second barrier protects buffer reuse.
// LDS XOR-swizzle: 16B-chunk q of row r holds global chunk q^(r&7) (rule #21:
// inverse-swizzled per-lane global source, linear LDS dest, swizzled ds_read).
// mode 0: store bf16 raw; 1: atomicAdd f32 (tap-split); 2: bf16 bias+relu.
// ---------------------------------------------------------------------------
__global__ __launch_bounds__(128, 2) void spconv_mfma(
    const __hip_bfloat16* __restrict__ feat, const int* __restrict__ nmap,
    const __hip_bfloat16* __restrict__ Wt, void* __restrict__ outp,
    const float* __restrict__ bias, int Nout, int K, int mode)
{
    __shared__ short Abuf[2][64 * 64];   // 16 KB
    __shared__ short Bbuf[2][64 * 64];   // 16 KB
    __shared__ int jl[27 * 64];          // 6.9 KB

    const int t = threadIdx.x;
    const int w = t >> 6, l = t & 63;
    const int row0 = blockIdx.x * 64;
    const int per = (K + gridDim.y - 1) / gridDim.y;
    const int kb0 = blockIdx.y * per;
    const int nk = min(K, kb0 + per) - kb0;

    for (int i = t; i < nk * 64; i += 128) {
        int k = i >> 6, r = i & 63;
        jl[i] = nmap[(size_t)(row0 + r) * K + (kb0 + k)];
    }
    __syncthreads();   // jl visible (one-time drain is fine here)

    // staging: chunk c = t + i*128 (c in 0..511); row r=c>>3, chunk q=c&7;
    // LDS linear at c*16B; global source chunk q^(r&7) (inverse swizzle).
    auto stage = [&](int buf, int k) {
        const __hip_bfloat16* Wk = Wt + (size_t)(kb0 + k) * 4096;
        const int kbase = k << 6;
#pragma unroll
        for (int i = 0; i < 4; ++i) {
            int c = t + i * 128;
            int r = c >> 3;
            int q = (c & 7) ^ (r & 7);
            int j = jl[kbase + r];
            __builtin_amdgcn_global_load_lds(
                (const __attribute__((address_space(1))) void*)(feat + ((size_t)j << 6) + (q << 3)),
                (__attribute__((address_space(3))) void*)&Abuf[buf][c << 3],
                16, 0, 0);
            __builtin_amdgcn_global_load_lds(
                (const __attribute__((address_space(1))) void*)(Wk + (r << 6) + (q << 3)),
                (__attribute__((address_space(3))) void*)&Bbuf[buf][c << 3],
                16, 0, 0);
        }
    };

    f32x4 acc[2][4] = {};
    const int lr = l & 15, lh = l >> 4;

    stage(0, 0);                    // 8 loads in flight

    int cur = 0;
    for (int k = 0; k < nk; ++k) {
        if (k + 1 < nk) {
            stage(cur ^ 1, k + 1);  // +8 -> 16 outstanding
            asm volatile("s_waitcnt vmcnt(8)" ::: "memory");   // tile k landed
        } else {
            asm volatile("s_waitcnt vmcnt(0)" ::: "memory");
        }
        asm volatile("s_barrier" ::: "memory");   // B1: tile k visible to all
        const short* Ab = Abuf[cur];
        const short* Bb = Bbuf[cur];
#pragma unroll
        for (int kk = 0; kk < 2; ++kk) {
            int q = (kk << 2) + lh;
            int ar0 = (w << 5) + lr;
            int ar1 = ar0 + 16;
            short8 a0 = *(const short8*)&Ab[(ar0 << 6) + ((q ^ (ar0 & 7)) << 3)];
            short8 a1 = *(const short8*)&Ab[(ar1 << 6) + ((q ^ (ar1 & 7)) << 3)];
#pragma unroll
            for (int ct = 0; ct < 4; ++ct) {
                int dr = (ct << 4) + lr;
                short8 b = *(const short8*)&Bb[(dr << 6) + ((q ^ (dr & 7)) << 3)];
                acc[0][ct] = __builtin_amdgcn_mfma_f32_16x16x32_bf16(a0, b, acc[0][ct], 0, 0, 0);
                acc[1][ct] = __builtin_amdgcn_mfma_f32_16x16x32_bf16(a1, b, acc[1][ct], 0, 0, 0);
            }
        }
        asm volatile("s_barrier" ::: "memory");   // B2: reads done before overwrite
        cur ^= 1;
    }

    // epilogue: C/D layout col = lane&15 (+ct*16), row = (lane>>4)*4 + reg
    if (mode == 1) {
        float* o32 = (float*)outp;
#pragma unroll
        for (int rt = 0; rt < 2; ++rt)
#pragma unroll
            for (int ct = 0; ct < 4; ++ct) {
                int col = (ct << 4) + lr;
#pragma unroll
                for (int rr = 0; rr < 4; ++rr) {
                    int row = row0 + (w << 5) + (rt << 4) + (lh << 2) + rr;
                    atomicAdd(&o32[((size_t)row << 6) + col], acc[rt][ct][rr]);
                }
            }
    } else {
        __hip_bfloat16* ob = (__hip_bfloat16*)outp;
#pragma unroll
        for (int rt = 0; rt < 2; ++rt)
#pragma unroll
            for (int ct = 0; ct < 4; ++ct) {
                int col = (ct << 4) + lr;
                float bv = (mode == 2) ? bias[col] : 0.f;
#pragma unroll
                for (int rr = 0; rr < 4; ++rr) {
                    int row = row0 + (w << 5) + (rt << 4) + (lh << 2) + rr;
                    float v = acc[rt][ct][rr];
                    if (mode == 2) v = fmaxf(v + bv, 0.f);
                    ob[((size_t)row << 6) + col] = __float2bfloat16(v);
                }
            }
    }
}

// ---------------------------------------------------------------------------
// epi_relu_bf: out_bf16 = relu(in_f32 + bias[c])  over [N][64]
// ---------------------------------------------------------------------------
__global__ void epi_relu_bf(const float* __restrict__ in, const float* __restrict__ bias,
                            __hip_bfloat16* __restrict__ outb, int nv)
{
    int i = blockIdx.x * blockDim.x + threadIdx.x;
    if (i >= nv) return;
    float4 v = ((const float4*)in)[i];
    int c = (i << 2) & 63;
    ushort4 o;
    o.x = __builtin_bit_cast(unsigned short, __float2bfloat16(fmaxf(v.x + bias[c + 0], 0.f)));
    o.y = __builtin_bit_cast(unsigned short, __float2bfloat16(fmaxf(v.y + bias[c + 1], 0.f)));
    o.z = __builtin_bit_cast(unsigned short, __float2bfloat16(fmaxf(v.z + bias[c + 2], 0.f)));
    o.w = __builtin_bit_cast(unsigned short, __float2bfloat16(fmaxf(v.w + bias[c + 3], 0.f)));
    ((ushort4*)outb)[i] = o;
}

// ---------------------------------------------------------------------------
// epi_full: thread-per-row, LDS-staged weights (broadcast reads), fully
// unrolled register arrays. t = act(src); hx = t@Wout+bout -> hx_out;
// g = sigmoid(hx@Wg+bg); gout = bf16(g*t).
// smode 0: src bf16 +bias+relu; 1: src f32 +bias+relu; 2: src f32 raw.
// ---------------------------------------------------------------------------
__global__ __launch_bounds__(256) void epi_full(
    const void* __restrict__ srcp, int smode, const float* __restrict__ bconv,
    const float* __restrict__ Wout, const float* __restrict__ bout,
    const float* __restrict__ Wg, const float* __restrict__ bg,
    float* __restrict__ hx_out, __hip_bfloat16* __restrict__ gout, int N)
{
    __shared__ float Woutl[64 * 32];
    __shared__ float Wgl[32 * 64];
    __shared__ float boutl[32];
    __shared__ float bgl[64];
    __shared__ float bcl[64];

    const int t = threadIdx.x;
    for (int i = t; i < 2048; i += 256) { Woutl[i] = Wout[i]; Wgl[i] = Wg[i]; }
    if (t < 32) boutl[t] = bout[t];
    if (t >= 64 && t < 128) bgl[t - 64] = bg[t - 64];
    if (t >= 128 && t < 192) bcl[t - 128] = bconv ? bconv[t - 128] : 0.f;
    __syncthreads();

    const int row = blockIdx.x * 256 + t;

    float tv[64];
    if (smode == 0) {
        const ushort4* sb = (const ushort4*)((const __hip_bfloat16*)srcp + ((size_t)row << 6));
#pragma unroll
        for (int i = 0; i < 16; ++i) {
            ushort4 v = sb[i];
            tv[i * 4 + 0] = __bfloat162float(__builtin_bit_cast(__hip_bfloat16, v.x));
            tv[i * 4 + 1] = __bfloat162float(__builtin_bit_cast(__hip_bfloat16, v.y));
            tv[i * 4 + 2] = __bfloat162float(__builtin_bit_cast(__hip_bfloat16, v.z));
            tv[i * 4 + 3] = __bfloat162float(__builtin_bit_cast(__hip_bfloat16, v.w));
        }
    } else {
        const float4* sf = (const float4*)((const float*)srcp + ((size_t)row << 6));
#pragma unroll
        for (int i = 0; i < 16; ++i) {
            float4 v = sf[i];
            tv[i * 4 + 0] = v.x; tv[i * 4 + 1] = v.y;
            tv[i * 4 + 2] = v.z; tv[i * 4 + 3] = v.w;
        }
    }
    if (smode != 2) {
#pragma unroll
        for (int c = 0; c < 64; ++c) tv[c] = fmaxf(tv[c] + bcl[c], 0.f);
    }

    float hx[32];
#pragma unroll
    for (int d = 0; d < 32; ++d) hx[d] = boutl[d];
#pragma unroll
    for (int c = 0; c < 64; ++c) {
        float tc = tv[c];
        const f32x4* wr = (const f32x4*)&Woutl[c << 5];
#pragma unroll
        for (int d4 = 0; d4 < 8; ++d4) {
            f32x4 wv = wr[d4];
            hx[d4 * 4 + 0] = fmaf(tc, wv[0], hx[d4 * 4 + 0]);
            hx[d4 * 4 + 1] = fmaf(tc, wv[1], hx[d4 * 4 + 1]);
            hx[d4 * 4 + 2] = fmaf(tc, wv[2], hx[d4 * 4 + 2]);
            hx[d4 * 4 + 3] = fmaf(tc, wv[3], hx[d4 * 4 + 3]);
        }
    }
    {
        float* ho = hx_out + ((size_t)row << 5);
#pragma unroll
        for (int i = 0; i < 8; ++i) {
            float4 v = {hx[i * 4 + 0], hx[i * 4 + 1], hx[i * 4 + 2], hx[i * 4 + 3]};
            ((float4*)ho)[i] = v;
        }
    }

    __hip_bfloat16* go = gout + ((size_t)row << 6);
#pragma unroll
    for (int jc = 0; jc < 2; ++jc) {
        float acc[32];
#pragma unroll
        for (int jj = 0; jj < 32; ++jj) acc[jj] = bgl[jc * 32 + jj];
#pragma unroll
        for (int d = 0; d < 32; ++d) {
            float hd = hx[d];
            const f32x4* wr = (const f32x4*)&Wgl[(d << 6) + jc * 32];
#pragma unroll
            for (int j4 = 0; j4 < 8; ++j4) {
                f32x4 wv = wr[j4];
                acc[j4 * 4 + 0] = fmaf(hd, wv[0], acc[j4 * 4 + 0]);
                acc[j4 * 4 + 1] = fmaf(hd, wv[1], acc[j4 * 4 + 1]);
                acc[j4 * 4 + 2] = fmaf(hd, wv[2], acc[j4 * 4 + 2]);
                acc[j4 * 4 + 3] = fmaf(hd, wv[3], acc[j4 * 4 + 3]);
            }
        }
        unsigned short ob[32];
#pragma unroll
        for (int jj = 0; jj < 32; ++jj) {
            float gg = 1.f / (1.f + __expf(-acc[jj]));
            ob[jj] = __builtin_bit_cast(unsigned short,
                         __float2bfloat16(gg * tv[jc * 32 + jj]));
        }
#pragma unroll
        for (int i = 0; i < 8; ++i) {
            ushort4 v = {ob[i * 4 + 0], ob[i * 4 + 1], ob[i * 4 + 2], ob[i * 4 + 3]};
            ((ushort4*)go)[jc * 8 + i] = v;
        }
    }
}

// ---------------------------------------------------------------------------
extern "C" void kernel_launch(void* const* d_in, const int* in_sizes, int n_in,
                              void* d_out, int out_size, void* d_ws, size_t ws_size,
                              hipStream_t stream)
{
    const float* x    = (const float*)d_in[0];
    const float* Wg0  = (const float*)d_in[1];
    const float* bg0  = (const float*)d_in[2];
    const float* Wg1  = (const float*)d_in[3];
    const float* bg1  = (const float*)d_in[4];
    const float* Wout = (const float*)d_in[5];
    const float* bout = (const float*)d_in[6];
    const float* WA   = (const float*)d_in[7];
    const float* bA   = (const float*)d_in[8];
    const float* WB   = (const float*)d_in[9];
    const float* bB   = (const float*)d_in[10];
    const float* WD   = (const float*)d_in[11];
    const float* bD   = (const float*)d_in[12];
    const float* WC   = (const float*)d_in[13];
    const float* bC   = (const float*)d_in[14];
    const int* nmap[4] = {(const int*)d_in[15], (const int*)d_in[16],
                          (const int*)d_in[17], (const int*)d_in[18]};
    const int* ndm[3]  = {(const int*)d_in[19], (const int*)d_in[20],
                          (const int*)d_in[21]};

    float* out = (float*)d_out;
    __hip_bfloat16* featbf0 = (__hip_bfloat16*)d_ws;
    __hip_bfloat16* featbf1 = featbf0 + (size_t)N0 * 64;
    __hip_bfloat16* convbf  = featbf1 + (size_t)N0 * 64;
    float* conv32 = (float*)(convbf + (size_t)N0 * 64);
    __hip_bfloat16* WAt = (__hip_bfloat16*)(conv32 + (size_t)N2 * 64);
    __hip_bfloat16* WBt = WAt + 27 * 4096;
    __hip_bfloat16* WCt = WBt + 27 * 4096;
    __hip_bfloat16* WDt = WCt + 27 * 4096;

    const int Ns[4] = {N0, N1, N2, N3};
    size_t off[7];
    off[0] = 0;
    off[1] = off[0] + (size_t)N0 * 32;
    off[2] = off[1] + (size_t)N0 * 32;
    off[3] = off[2] + (size_t)N1 * 32;
    off[4] = off[3] + (size_t)N1 * 32;
    off[5] = off[4] + (size_t)N2 * 32;
    off[6] = off[5] + (size_t)N2 * 32;

    hipLaunchKernelGGL(prep_w4, dim3((89 * 4096 + 255) / 256), dim3(256), 0, stream,
                       WA, WB, WC, WD, WAt, 89 * 4096);

    // chunks: big scales run direct (ch=1); small scales tap-split via f32 atomics
    auto chunks = [&](int Nout, int K) -> int {
        if (Nout >= 16384) return 1;
        if (Nout == 4096) return (K == 27) ? 4 : 2;
        return (K == 27) ? 7 : 4;   // N3
    };
    // returns 1 if result is f32 in conv32, else 0 (bf16 in dst)
    auto conv = [&](const __hip_bfloat16* fin, const int* nm,
                    const __hip_bfloat16* Wt, int Nout, int K,
                    const float* bias2, void* dst, int mode) -> int {
        int ch = chunks(Nout, K);
        if (ch > 1) {
            hipMemsetAsync(conv32, 0, (size_t)Nout * 64 * sizeof(float), stream);
            hipLaunchKernelGGL(spconv_mfma, dim3(Nout / 64, ch), dim3(128), 0, stream,
                               fin, nm, Wt, (void*)conv32, (const float*)nullptr,
                               Nout, K, 1);
            return 1;
        }
        hipLaunchKernelGGL(spconv_mfma, dim3(Nout / 64, 1), dim3(128), 0, stream,
                           fin, nm, Wt, dst, bias2, Nout, K, mode);
        return 0;
    };

    // init: hx0 -> out0 ; featbf0 = bf16(sigmoid(hx0@Wg0+bg0) * x)
    hipLaunchKernelGGL(epi_full, dim3(N0 / 256), dim3(256), 0, stream,
                       (const void*)x, 2, (const float*)nullptr, Wout, bout, Wg0, bg0,
                       out + off[0], featbf0, N0);

    for (int s = 0; s < 3; ++s) {
        int N = Ns[s], Nn = Ns[s + 1];

        // conv A (bias+relu) -> featbf1
        int mA = conv(featbf0, nmap[s], WAt, N, 27, bA, featbf1, 2);
        if (mA)
            hipLaunchKernelGGL(epi_relu_bf, dim3((N * 16 + 255) / 256), dim3(256), 0, stream,
                               conv32, bA, featbf1, N * 16);
        // conv B (raw) -> convbf/conv32 ; epilogue fuses bias+relu+hx+gate
        int mB = conv(featbf1, nmap[s], WBt, N, 27, nullptr, convbf, 0);
        hipLaunchKernelGGL(epi_full, dim3(N / 256), dim3(256), 0, stream,
                           mB ? (const void*)conv32 : (const void*)convbf, mB, bB,
                           Wout, bout, Wg1, bg1, out + off[s * 2 + 1], featbf0, N);

        // conv D (downsample, bias+relu) -> featbf1
        int mD = conv(featbf0, ndm[s], WDt, Nn, 8, bD, featbf1, 2);
        if (mD)
            hipLaunchKernelGGL(epi_relu_bf, dim3((Nn * 16 + 255) / 256), dim3(256), 0, stream,
                               conv32, bD, featbf1, Nn * 16);
        // conv C (raw) -> convbf/conv32 ; epilogue
        int mC = conv(featbf1, nmap[s + 1], WCt, Nn, 27, nullptr, convbf, 0);
        hipLaunchKernelGGL(epi_full, dim3(Nn / 256), dim3(256), 0, stream,
                           mC ? (const void*)conv32 : (const void*)convbf, mC, bC,
                           Wout, bout, Wg0, bg0, out + off[s * 2 + 2], featbf0, Nn);
    }
}